// Round 1
// baseline (2755.598 us; speedup 1.0000x reference)
//
#include <hip/hip_runtime.h>
#include <hip/hip_bf16.h>

typedef unsigned int u32;
typedef unsigned short u16;

struct WPtrs { const void* p[19]; };

// ---- wsW float layout ----
// 0:W1[160] 160:b1[16] 176:W2[256] 432:b2[16] 448:Wz[256] 704:bz[16] 720:Wr[256]
// 976:br[16] 992:Wh[256] 1248:bh[16] 1264:Lz[512] 1776:lz[16] 1792:Lr[512] 2304:lr[16]
// 2320:Lh[512] 2832:lh[16] 2848:att[5] 2853:fcW[32] 2885:fcb[2]
// derived: 2944:Az[256] 3200:Ar[256] 3456:Ah[256] 3712:cz[16] 3728:cr[16] 3744:ch[16]

__device__ __forceinline__ float sigm(float x){ return 1.0f/(1.0f+__expf(-x)); }

__global__ __launch_bounds__(256)
void k_prep(const void* __restrict__ x, WPtrs wp, int* __restrict__ flagp,
            float* __restrict__ wsW)
{
    __shared__ int scount;
    __shared__ int sflag;
    if (threadIdx.x == 0) scount = 0;
    __syncthreads();
    // dtype probe: sample even u16 indices of x. bf16 data => exponent field
    // almost always in [110,140]; f32 low-halves => uniform (P~0.12).
    const u16* xs = (const u16*)x;
    int cnt = 0;
    #pragma unroll
    for (int j = 0; j < 8; j++) {
        int k = (threadIdx.x*8 + j) * 1201;     // < 2.46M, safe for both dtypes
        u16 u = xs[2*k];
        int ex = (u >> 7) & 0xFF;
        cnt += (ex >= 110 && ex <= 140) ? 1 : 0;
    }
    atomicAdd(&scount, cnt);
    __syncthreads();
    if (threadIdx.x == 0) { sflag = (scount > 1024) ? 1 : 0; flagp[0] = sflag; }
    __syncthreads();
    const int flag = sflag;

    const int sizes[19] = {160,16,256,16,256,16,256,16,256,16,512,16,512,16,512,16,5,32,2};
    int off = 0;
    for (int a = 0; a < 19; a++) {
        const void* s = wp.p[a];
        for (int j = threadIdx.x; j < sizes[a]; j += 256) {
            float v = flag ? __bfloat162float(((const __hip_bfloat16*)s)[j])
                           : ((const float*)s)[j];
            wsW[off + j] = v;
        }
        off += sizes[a];
    }
    __syncthreads();
    // derived: Az = Wz @ Lz_top etc., cz = bz @ Lz_top + lz etc.
    {
        int k = threadIdx.x >> 4, j = threadIdx.x & 15;
        float az = 0.f, ar = 0.f, ah = 0.f;
        #pragma unroll
        for (int m = 0; m < 16; m++) {
            az += wsW[448 + k*16 + m] * wsW[1264 + m*16 + j];
            ar += wsW[720 + k*16 + m] * wsW[1792 + m*16 + j];
            ah += wsW[992 + k*16 + m] * wsW[2320 + m*16 + j];
        }
        wsW[2944 + threadIdx.x] = az;
        wsW[3200 + threadIdx.x] = ar;
        wsW[3456 + threadIdx.x] = ah;
        if (threadIdx.x < 16) {
            float cz = wsW[1776 + j], cr = wsW[2304 + j], ch = wsW[2832 + j];
            #pragma unroll
            for (int m = 0; m < 16; m++) {
                cz += wsW[704  + m] * wsW[1264 + m*16 + j];
                cr += wsW[976  + m] * wsW[1792 + m*16 + j];
                ch += wsW[1248 + m] * wsW[2320 + m*16 + j];
            }
            wsW[3712 + j] = cz; wsW[3728 + j] = cr; wsW[3744 + j] = ch;
        }
    }
}

__global__ __launch_bounds__(256)
void k_deg(const int* __restrict__ dst, int* __restrict__ deg, int E)
{
    int e = blockIdx.x*256 + threadIdx.x;
    if (e < E) atomicAdd(&deg[dst[e]], 1);
}

__global__ __launch_bounds__(256)
void k_scan_a(const int* __restrict__ deg, float* __restrict__ dis,
              float* __restrict__ dinv, int* __restrict__ bsum, int N)
{
    __shared__ int sm[256];
    int i = blockIdx.x*256 + threadIdx.x;
    int c = (i < N) ? deg[i] : 0;
    if (i < N) {
        float d = (float)(c + 1);
        dis[i]  = rsqrtf(d);
        dinv[i] = 1.0f / d;
    }
    sm[threadIdx.x] = c; __syncthreads();
    for (int s = 128; s > 0; s >>= 1) {
        if (threadIdx.x < s) sm[threadIdx.x] += sm[threadIdx.x + s];
        __syncthreads();
    }
    if (threadIdx.x == 0) bsum[blockIdx.x] = sm[0];
}

__global__ void k_scan_b(const int* __restrict__ bsum, int* __restrict__ boff, int nb)
{
    __shared__ int sm[512];
    int t = threadIdx.x;
    int v = (t < nb) ? bsum[t] : 0;
    sm[t] = v; __syncthreads();
    for (int s = 1; s < 512; s <<= 1) {
        int add = (t >= s) ? sm[t - s] : 0;
        __syncthreads();
        sm[t] += add;
        __syncthreads();
    }
    if (t < nb) boff[t] = sm[t] - v;   // exclusive
}

__global__ __launch_bounds__(256)
void k_scan_c(const int* __restrict__ deg, const int* __restrict__ boff,
              int* __restrict__ row_start, int* __restrict__ cursor, int N, int E)
{
    __shared__ int sm[256];
    int t = threadIdx.x;
    int i = blockIdx.x*256 + t;
    int c = (i < N) ? deg[i] : 0;
    sm[t] = c; __syncthreads();
    for (int s = 1; s < 256; s <<= 1) {
        int add = (t >= s) ? sm[t - s] : 0;
        __syncthreads();
        sm[t] += add;
        __syncthreads();
    }
    int rs = boff[blockIdx.x] + sm[t] - c;
    if (i < N) {
        row_start[i] = rs;
        cursor[i]    = rs;
        if (i == N - 1) row_start[N] = rs + c;   // == E
    }
}

__global__ __launch_bounds__(256)
void k_fill(const int* __restrict__ src, const int* __restrict__ dst,
            const float* __restrict__ dis, int* __restrict__ cursor,
            int2* __restrict__ csr, int E)
{
    int e = blockIdx.x*256 + threadIdx.x;
    if (e < E) {
        int s = src[e], d = dst[e];
        int pos = atomicAdd(&cursor[d], 1);
        csr[pos] = make_int2(s, __float_as_int(dis[s]));
    }
}

// P0 = deg_inv*x + sum_in enorm*x[src], batched over all T: B1 layout [N][50]
__global__ __launch_bounds__(256)
void k_gatherA(const void* __restrict__ x, const int* __restrict__ flagp,
               const float* __restrict__ dis, const float* __restrict__ dinv,
               const int* __restrict__ row_start, const int2* __restrict__ csr,
               float* __restrict__ B1, int N)
{
    int tid = blockIdx.x*256 + threadIdx.x;
    if (tid >= N*50) return;
    int i = tid / 50, c = tid - i*50;
    int t = c / 10, f = c - t*10;
    int flag = flagp[0];
    const __hip_bfloat16* xb = (const __hip_bfloat16*)x;
    const float*          xf = (const float*)x;
    int base = t*N*10 + f;
    float acc;
    {
        int idx = base + i*10;
        float v = flag ? __bfloat162float(xb[idx]) : xf[idx];
        acc = dinv[i] * v;
    }
    float dd = dis[i];
    int rs = row_start[i], re = row_start[i+1];
    if (flag) {
        for (int k = rs; k < re; k++) {
            int2 sw = csr[k];
            acc += dd * __int_as_float(sw.y) * __bfloat162float(xb[base + sw.x*10]);
        }
    } else {
        for (int k = rs; k < re; k++) {
            int2 sw = csr[k];
            acc += dd * __int_as_float(sw.y) * xf[base + sw.x*10];
        }
    }
    B1[tid] = acc;
}

// generic 80-feature propagation: Fout = deg_inv*Fin + sum_in enorm*Fin[src]
__global__ __launch_bounds__(256)
void k_gatherF(const float* __restrict__ Fin, const float* __restrict__ dis,
               const float* __restrict__ dinv, const int* __restrict__ row_start,
               const int2* __restrict__ csr, float* __restrict__ Fout, int N)
{
    int tid = blockIdx.x*256 + threadIdx.x;
    if (tid >= N*80) return;
    int i = tid / 80, c = tid - i*80;
    float acc = dinv[i] * Fin[i*80 + c];
    float dd = dis[i];
    int rs = row_start[i], re = row_start[i+1];
    for (int k = rs; k < re; k++) {
        int2 sw = csr[k];
        acc += dd * __int_as_float(sw.y) * Fin[sw.x*80 + c];
    }
    Fout[tid] = acc;
}

// h1 = relu(P0 @ W1 + b1): B1[N][50] -> B2[N][80]
__global__ __launch_bounds__(256)
void k_dense1(const float* __restrict__ B1, const float* __restrict__ wsW,
              float* __restrict__ B2, int N)
{
    __shared__ float w[176];
    for (int j = threadIdx.x; j < 176; j += 256) w[j] = wsW[j];
    __syncthreads();
    int tid = blockIdx.x*256 + threadIdx.x;
    if (tid >= N*5) return;
    int i = tid / 5, t = tid - i*5;
    float p[10];
    #pragma unroll
    for (int f = 0; f < 10; f++) p[f] = B1[i*50 + t*10 + f];
    float* out = B2 + i*80 + t*16;
    #pragma unroll
    for (int jb = 0; jb < 4; jb++) {
        float4 h = ((const float4*)&w[160])[jb];
        #pragma unroll
        for (int f = 0; f < 10; f++) {
            float4 wv = ((const float4*)w)[f*4 + jb];
            h.x += p[f]*wv.x; h.y += p[f]*wv.y; h.z += p[f]*wv.z; h.w += p[f]*wv.w;
        }
        h.x = fmaxf(h.x, 0.f); h.y = fmaxf(h.y, 0.f);
        h.z = fmaxf(h.z, 0.f); h.w = fmaxf(h.w, 0.f);
        ((float4*)out)[jb] = h;
    }
}

// feats = relu(P1 @ W2 + b2): B1[N][80] -> B2[N][80]
__global__ __launch_bounds__(256)
void k_dense2(const float* __restrict__ B1, const float* __restrict__ wsW,
              float* __restrict__ B2, int N)
{
    __shared__ float w[272];   // W2 (256) + b2 (16)
    for (int j = threadIdx.x; j < 272; j += 256) w[j] = wsW[176 + j];
    __syncthreads();
    int tid = blockIdx.x*256 + threadIdx.x;
    if (tid >= N*5) return;
    int i = tid / 5, t = tid - i*5;
    float p[16];
    #pragma unroll
    for (int f = 0; f < 16; f++) p[f] = B1[i*80 + t*16 + f];
    float* out = B2 + i*80 + t*16;
    #pragma unroll
    for (int jb = 0; jb < 4; jb++) {
        float4 h = ((const float4*)&w[256])[jb];
        #pragma unroll
        for (int f = 0; f < 16; f++) {
            float4 wv = ((const float4*)w)[f*4 + jb];
            h.x += p[f]*wv.x; h.y += p[f]*wv.y; h.z += p[f]*wv.z; h.w += p[f]*wv.w;
        }
        h.x = fmaxf(h.x, 0.f); h.y = fmaxf(h.y, 0.f);
        h.z = fmaxf(h.z, 0.f); h.w = fmaxf(h.w, 0.f);
        ((float4*)out)[jb] = h;
    }
}

// GRU over 5 steps + attention pool + FC + log_softmax, one thread per node.
// LDS layout (floats): 0:Az 256:Ar 512:Ah 768:LzB 1024:LrB 1280:LhB
//                      1536:cz 1552:cr 1568:ch 1584:att[5] 1592:fcW[32] 1624:fcb[2]
__global__ __launch_bounds__(256)
void k_gru(const float* __restrict__ Pf, const float* __restrict__ wsW,
           const int* __restrict__ flagp, void* __restrict__ out, int N)
{
    __shared__ __align__(16) float sm[1632];
    const int tbl[12][3] = {
        {2944,0,256},{3200,256,256},{3456,512,256},
        {1520,768,256},{2048,1024,256},{2576,1280,256},
        {3712,1536,16},{3728,1552,16},{3744,1568,16},
        {2848,1584,5},{2853,1592,32},{2885,1624,2}};
    for (int a = 0; a < 12; a++)
        for (int j = threadIdx.x; j < tbl[a][2]; j += 256)
            sm[tbl[a][1] + j] = wsW[tbl[a][0] + j];
    __syncthreads();

    int i = blockIdx.x*256 + threadIdx.x;
    if (i >= N) return;

    // attention probs
    float a0=sm[1584],a1=sm[1585],a2=sm[1586],a3=sm[1587],a4=sm[1588];
    float am = fmaxf(fmaxf(fmaxf(a0,a1),fmaxf(a2,a3)),a4);
    float e0=__expf(a0-am),e1=__expf(a1-am),e2=__expf(a2-am),e3=__expf(a3-am),e4=__expf(a4-am);
    float inv = 1.f/(e0+e1+e2+e3+e4);
    float pr[5] = {e0*inv,e1*inv,e2*inv,e3*inv,e4*inv};

    const float4* Az4 = (const float4*)&sm[0];
    const float4* Ar4 = (const float4*)&sm[256];
    const float4* Ah4 = (const float4*)&sm[512];
    const float4* Lz4 = (const float4*)&sm[768];
    const float4* Lr4 = (const float4*)&sm[1024];
    const float4* Lh4 = (const float4*)&sm[1280];

    float H[16], Hacc[16];
    #pragma unroll
    for (int j = 0; j < 16; j++) { H[j] = 0.f; Hacc[j] = 0.f; }

    for (int t = 0; t < 5; t++) {
        const float* prow = Pf + i*80 + t*16;
        float pf[16];
        #pragma unroll
        for (int j = 0; j < 16; j++) pf[j] = prow[j];

        float za[16], ra[16], ha[16];
        #pragma unroll
        for (int jb = 0; jb < 4; jb++) {
            float4 az = ((const float4*)&sm[1536])[jb];
            float4 ar = ((const float4*)&sm[1552])[jb];
            float4 ah = ((const float4*)&sm[1568])[jb];
            #pragma unroll
            for (int k = 0; k < 16; k++) {
                float p = pf[k];
                float4 wz = Az4[k*4+jb], wr = Ar4[k*4+jb], wh = Ah4[k*4+jb];
                az.x += p*wz.x; az.y += p*wz.y; az.z += p*wz.z; az.w += p*wz.w;
                ar.x += p*wr.x; ar.y += p*wr.y; ar.z += p*wr.z; ar.w += p*wr.w;
                ah.x += p*wh.x; ah.y += p*wh.y; ah.z += p*wh.z; ah.w += p*wh.w;
            }
            za[jb*4+0]=az.x; za[jb*4+1]=az.y; za[jb*4+2]=az.z; za[jb*4+3]=az.w;
            ra[jb*4+0]=ar.x; ra[jb*4+1]=ar.y; ra[jb*4+2]=ar.z; ra[jb*4+3]=ar.w;
            ha[jb*4+0]=ah.x; ha[jb*4+1]=ah.y; ha[jb*4+2]=ah.z; ha[jb*4+3]=ah.w;
        }

        float Zg[16], Rg[16];
        #pragma unroll
        for (int jb = 0; jb < 4; jb++) {
            float4 az = make_float4(za[jb*4],za[jb*4+1],za[jb*4+2],za[jb*4+3]);
            float4 ar = make_float4(ra[jb*4],ra[jb*4+1],ra[jb*4+2],ra[jb*4+3]);
            #pragma unroll
            for (int k = 0; k < 16; k++) {
                float h = H[k];
                float4 lz = Lz4[k*4+jb], lr = Lr4[k*4+jb];
                az.x += h*lz.x; az.y += h*lz.y; az.z += h*lz.z; az.w += h*lz.w;
                ar.x += h*lr.x; ar.y += h*lr.y; ar.z += h*lr.z; ar.w += h*lr.w;
            }
            Zg[jb*4+0]=sigm(az.x); Zg[jb*4+1]=sigm(az.y); Zg[jb*4+2]=sigm(az.z); Zg[jb*4+3]=sigm(az.w);
            Rg[jb*4+0]=sigm(ar.x); Rg[jb*4+1]=sigm(ar.y); Rg[jb*4+2]=sigm(ar.z); Rg[jb*4+3]=sigm(ar.w);
        }

        float HR[16];
        #pragma unroll
        for (int k = 0; k < 16; k++) HR[k] = H[k]*Rg[k];

        #pragma unroll
        for (int jb = 0; jb < 4; jb++) {
            float4 ah = make_float4(ha[jb*4],ha[jb*4+1],ha[jb*4+2],ha[jb*4+3]);
            #pragma unroll
            for (int k = 0; k < 16; k++) {
                float h = HR[k];
                float4 lh = Lh4[k*4+jb];
                ah.x += h*lh.x; ah.y += h*lh.y; ah.z += h*lh.z; ah.w += h*lh.w;
            }
            #pragma unroll
            for (int q = 0; q < 4; q++) {
                int j = jb*4 + q;
                float v = (q==0)?ah.x:(q==1)?ah.y:(q==2)?ah.z:ah.w;
                v = fminf(fmaxf(v, -15.f), 15.f);
                float ex = __expf(2.f*v);
                float th = (ex - 1.f) / (ex + 1.f);
                float z = Zg[j];
                H[j] = z*H[j] + (1.f - z)*th;
                Hacc[j] += pr[t]*H[j];
            }
        }
    }

    float z0 = sm[1624], z1 = sm[1625];
    #pragma unroll
    for (int k = 0; k < 16; k++) {
        z0 += Hacc[k]*sm[1592 + k*2];
        z1 += Hacc[k]*sm[1592 + k*2 + 1];
    }
    float mm = fmaxf(z0, z1);
    float l  = __logf(__expf(z0-mm) + __expf(z1-mm));
    float o0 = z0 - mm - l, o1 = z1 - mm - l;
    if (flagp[0]) {
        __hip_bfloat162 h2;
        h2.x = __float2bfloat16(o0);
        h2.y = __float2bfloat16(o1);
        ((__hip_bfloat162*)out)[i] = h2;
    } else {
        float2 f2 = make_float2(o0, o1);
        ((float2*)out)[i] = f2;
    }
}

extern "C" void kernel_launch(void* const* d_in, const int* in_sizes, int n_in,
                              void* d_out, int out_size, void* d_ws, size_t ws_size,
                              hipStream_t stream)
{
    const void* x   = d_in[0];
    const int* src  = (const int*)d_in[1];
    const int* dst  = (const int*)d_in[2];
    int N = in_sizes[0] / 50;     // T*F_IN = 50
    int E = in_sizes[1];

    char* ws = (char*)d_ws;
    size_t off = 0;
    auto alloc = [&](size_t bytes) -> void* {
        void* p = ws + off;
        off = (off + bytes + 255) & ~(size_t)255;
        return p;
    };
    int*   flagp     = (int*)  alloc(64);
    float* wsW       = (float*)alloc(4096*4);
    int*   deg       = (int*)  alloc((size_t)N*4);
    float* dis       = (float*)alloc((size_t)N*4);
    float* dinv      = (float*)alloc((size_t)N*4);
    int*   row_start = (int*)  alloc(((size_t)N+1)*4);
    int*   cursor    = (int*)  alloc((size_t)N*4);
    int*   bsum      = (int*)  alloc(4096);
    int*   boff      = (int*)  alloc(4096);
    int2*  csr       = (int2*) alloc((size_t)E*8);
    float* B1        = (float*)alloc((size_t)N*80*4);
    float* B2        = (float*)alloc((size_t)N*80*4);

    int nb = (N + 255) / 256;
    int gE = (E + 255) / 256;

    hipMemsetAsync(deg, 0, (size_t)N*4, stream);

    WPtrs wp;
    for (int a = 0; a < 19; a++) wp.p[a] = d_in[3 + a];
    k_prep<<<1, 256, 0, stream>>>(x, wp, flagp, wsW);

    k_deg   <<<gE, 256, 0, stream>>>(dst, deg, E);
    k_scan_a<<<nb, 256, 0, stream>>>(deg, dis, dinv, bsum, N);
    k_scan_b<<<1, 512, 0, stream>>>(bsum, boff, nb);
    k_scan_c<<<nb, 256, 0, stream>>>(deg, boff, row_start, cursor, N, E);
    k_fill  <<<gE, 256, 0, stream>>>(src, dst, dis, cursor, csr, E);

    int gA = ((size_t)N*50 + 255) / 256;
    int gF = ((size_t)N*80 + 255) / 256;
    int gD = ((size_t)N*5  + 255) / 256;

    k_gatherA<<<gA, 256, 0, stream>>>(x, flagp, dis, dinv, row_start, csr, B1, N);
    k_dense1 <<<gD, 256, 0, stream>>>(B1, wsW, B2, N);
    k_gatherF<<<gF, 256, 0, stream>>>(B2, dis, dinv, row_start, csr, B1, N);
    k_dense2 <<<gD, 256, 0, stream>>>(B1, wsW, B2, N);
    k_gatherF<<<gF, 256, 0, stream>>>(B2, dis, dinv, row_start, csr, B1, N);
    k_gru    <<<nb, 256, 0, stream>>>(B1, wsW, flagp, d_out, N);
}

// Round 2
// 2494.046 us; speedup vs baseline: 1.1049x; 1.1049x over previous
//
#include <hip/hip_runtime.h>
#include <hip/hip_bf16.h>

typedef unsigned int u32;
typedef unsigned short u16;

struct WPtrs { const void* p[19]; };

// ---- wsW float layout ----
// raw weights:
// 0:W1[160] 160:b1[16] 176:W2[256] 432:b2[16] 448:Wz[256] 704:bz[16] 720:Wr[256]
// 976:br[16] 992:Wh[256] 1248:bh[16] 1264:Lz[512] 1776:lz[16] 1792:Lr[512] 2304:lr[16]
// 2320:Lh[512] 2832:lh[16] 2848:att[5] 2853:fcW[32] 2885:fcb[2]
// derived: 2944:Az[256] 3200:Ar[256] 3456:Ah[256] 3712:cz[16] 3728:cr[16] 3744:ch[16]
// packed GRU block at 4096 (1632 floats):
//   +0:Az +256:Ar +512:Ah +768:LzB +1024:LrB +1280:LhB
//   +1536:cz +1552:cr +1568:ch +1584:pr[5] +1592:fcW[32] +1624:fcb[2]

__device__ __forceinline__ float sigm(float x){ return 1.0f/(1.0f+__expf(-x)); }

__global__ __launch_bounds__(256)
void k_prep(const void* __restrict__ x, WPtrs wp, int* __restrict__ flagp,
            float* __restrict__ wsW)
{
    __shared__ int scount;
    __shared__ int sflag;
    if (threadIdx.x == 0) scount = 0;
    __syncthreads();
    // dtype probe: sample even u16 indices of x. bf16 data => exponent field
    // almost always in [110,140]; f32 low-halves => uniform.
    const u16* xs = (const u16*)x;
    int cnt = 0;
    #pragma unroll
    for (int j = 0; j < 8; j++) {
        int k = (threadIdx.x*8 + j) * 1201;
        u16 u = xs[2*k];
        int ex = (u >> 7) & 0xFF;
        cnt += (ex >= 110 && ex <= 140) ? 1 : 0;
    }
    atomicAdd(&scount, cnt);
    __syncthreads();
    if (threadIdx.x == 0) { sflag = (scount > 1024) ? 1 : 0; flagp[0] = sflag; }
    __syncthreads();
    const int flag = sflag;

    const int sizes[19] = {160,16,256,16,256,16,256,16,256,16,512,16,512,16,512,16,5,32,2};
    int off = 0;
    for (int a = 0; a < 19; a++) {
        const void* s = wp.p[a];
        for (int j = threadIdx.x; j < sizes[a]; j += 256) {
            float v = flag ? __bfloat162float(((const __hip_bfloat16*)s)[j])
                           : ((const float*)s)[j];
            wsW[off + j] = v;
        }
        off += sizes[a];
    }
    __syncthreads();
    // derived: Az = Wz @ Lz_top etc., cz = bz @ Lz_top + lz etc.
    {
        int k = threadIdx.x >> 4, j = threadIdx.x & 15;
        float az = 0.f, ar = 0.f, ah = 0.f;
        #pragma unroll
        for (int m = 0; m < 16; m++) {
            az += wsW[448 + k*16 + m] * wsW[1264 + m*16 + j];
            ar += wsW[720 + k*16 + m] * wsW[1792 + m*16 + j];
            ah += wsW[992 + k*16 + m] * wsW[2320 + m*16 + j];
        }
        wsW[2944 + threadIdx.x] = az;
        wsW[3200 + threadIdx.x] = ar;
        wsW[3456 + threadIdx.x] = ah;
        if (threadIdx.x < 16) {
            float cz = wsW[1776 + j], cr = wsW[2304 + j], ch = wsW[2832 + j];
            #pragma unroll
            for (int m = 0; m < 16; m++) {
                cz += wsW[704  + m] * wsW[1264 + m*16 + j];
                cr += wsW[976  + m] * wsW[1792 + m*16 + j];
                ch += wsW[1248 + m] * wsW[2320 + m*16 + j];
            }
            wsW[3712 + j] = cz; wsW[3728 + j] = cr; wsW[3744 + j] = ch;
        }
    }
    __syncthreads();
    // pack GRU block
    {
        int j = threadIdx.x;
        wsW[4096 +        j] = wsW[2944 + j];   // Az
        wsW[4096 +  256 + j] = wsW[3200 + j];   // Ar
        wsW[4096 +  512 + j] = wsW[3456 + j];   // Ah
        wsW[4096 +  768 + j] = wsW[1520 + j];   // Lz bottom (rows 16..31)
        wsW[4096 + 1024 + j] = wsW[2048 + j];   // Lr bottom
        wsW[4096 + 1280 + j] = wsW[2576 + j];   // Lh bottom
        if (j < 16) {
            wsW[4096 + 1536 + j] = wsW[3712 + j];
            wsW[4096 + 1552 + j] = wsW[3728 + j];
            wsW[4096 + 1568 + j] = wsW[3744 + j];
        }
        if (j < 32) wsW[4096 + 1592 + j] = wsW[2853 + j];
        if (j < 2)  wsW[4096 + 1624 + j] = wsW[2885 + j];
        if (j == 0) {
            float a0=wsW[2848],a1=wsW[2849],a2=wsW[2850],a3=wsW[2851],a4=wsW[2852];
            float am = fmaxf(fmaxf(fmaxf(a0,a1),fmaxf(a2,a3)),a4);
            float e0=__expf(a0-am),e1=__expf(a1-am),e2=__expf(a2-am),
                  e3=__expf(a3-am),e4=__expf(a4-am);
            float inv = 1.f/(e0+e1+e2+e3+e4);
            wsW[4096+1584+0]=e0*inv; wsW[4096+1584+1]=e1*inv;
            wsW[4096+1584+2]=e2*inv; wsW[4096+1584+3]=e3*inv;
            wsW[4096+1584+4]=e4*inv;
        }
    }
}

__global__ __launch_bounds__(256)
void k_deg(const int* __restrict__ dst, int* __restrict__ deg, int E)
{
    int e = blockIdx.x*256 + threadIdx.x;
    if (e < E) atomicAdd(&deg[dst[e]], 1);
}

__global__ __launch_bounds__(256)
void k_scan_a(const int* __restrict__ deg, float* __restrict__ dis,
              float* __restrict__ dinv, int* __restrict__ bsum, int N)
{
    __shared__ int sm[256];
    int i = blockIdx.x*256 + threadIdx.x;
    int c = (i < N) ? deg[i] : 0;
    if (i < N) {
        float d = (float)(c + 1);
        dis[i]  = rsqrtf(d);
        dinv[i] = 1.0f / d;
    }
    sm[threadIdx.x] = c; __syncthreads();
    for (int s = 128; s > 0; s >>= 1) {
        if (threadIdx.x < s) sm[threadIdx.x] += sm[threadIdx.x + s];
        __syncthreads();
    }
    if (threadIdx.x == 0) bsum[blockIdx.x] = sm[0];
}

__global__ void k_scan_b(const int* __restrict__ bsum, int* __restrict__ boff, int nb)
{
    __shared__ int sm[512];
    int t = threadIdx.x;
    int v = (t < nb) ? bsum[t] : 0;
    sm[t] = v; __syncthreads();
    for (int s = 1; s < 512; s <<= 1) {
        int add = (t >= s) ? sm[t - s] : 0;
        __syncthreads();
        sm[t] += add;
        __syncthreads();
    }
    if (t < nb) boff[t] = sm[t] - v;   // exclusive
}

__global__ __launch_bounds__(256)
void k_scan_c(const int* __restrict__ deg, const int* __restrict__ boff,
              int* __restrict__ row_start, int* __restrict__ cursor, int N, int E)
{
    __shared__ int sm[256];
    int t = threadIdx.x;
    int i = blockIdx.x*256 + t;
    int c = (i < N) ? deg[i] : 0;
    sm[t] = c; __syncthreads();
    for (int s = 1; s < 256; s <<= 1) {
        int add = (t >= s) ? sm[t - s] : 0;
        __syncthreads();
        sm[t] += add;
        __syncthreads();
    }
    int rs = boff[blockIdx.x] + sm[t] - c;
    if (i < N) {
        row_start[i] = rs;
        cursor[i]    = rs;
        if (i == N - 1) row_start[N] = rs + c;   // == E
    }
}

__global__ __launch_bounds__(256)
void k_fill(const int* __restrict__ src, const int* __restrict__ dst,
            const float* __restrict__ dis, int* __restrict__ cursor,
            int2* __restrict__ csr, int E)
{
    int e = blockIdx.x*256 + threadIdx.x;
    if (e < E) {
        int s = src[e], d = dst[e];
        int pos = atomicAdd(&cursor[d], 1);
        csr[pos] = make_int2(s, __float_as_int(dis[s]));
    }
}

// pass 1 fused: per (node, slice): gather x (10 feats) then relu(@W1+b1) -> B[i][80]
__global__ __launch_bounds__(256)
void k_g1(const void* __restrict__ x, const int* __restrict__ flagp,
          const float* __restrict__ dis, const float* __restrict__ dinv,
          const int* __restrict__ row_start, const int2* __restrict__ csr,
          const float* __restrict__ wsW, float* __restrict__ B, int N)
{
    __shared__ float w[176];
    for (int j = threadIdx.x; j < 176; j += 256) w[j] = wsW[j];
    __syncthreads();
    int tid = blockIdx.x*256 + threadIdx.x;
    if (tid >= N*5) return;
    int i = tid / 5, t = tid - i*5;
    const int flag = flagp[0];

    float acc[10];
    float dd = dis[i];
    int rs = row_start[i], re = row_start[i+1];
    size_t selfb = ((size_t)t*N + i)*5;   // in units of 2 elements

    if (flag) {
        const __hip_bfloat162* xb = (const __hip_bfloat162*)x;
        float di = dinv[i];
        #pragma unroll
        for (int m = 0; m < 5; m++) {
            __hip_bfloat162 h2 = xb[selfb + m];
            acc[2*m]   = di*__bfloat162float(h2.x);
            acc[2*m+1] = di*__bfloat162float(h2.y);
        }
        for (int k = rs; k < re; k++) {
            int2 sw = csr[k];
            float wg = dd * __int_as_float(sw.y);
            size_t b = ((size_t)t*N + sw.x)*5;
            #pragma unroll
            for (int m = 0; m < 5; m++) {
                __hip_bfloat162 h2 = xb[b + m];
                acc[2*m]   += wg*__bfloat162float(h2.x);
                acc[2*m+1] += wg*__bfloat162float(h2.y);
            }
        }
    } else {
        const float2* xf = (const float2*)x;
        float di = dinv[i];
        #pragma unroll
        for (int m = 0; m < 5; m++) {
            float2 f2 = xf[selfb + m];
            acc[2*m]   = di*f2.x;
            acc[2*m+1] = di*f2.y;
        }
        for (int k = rs; k < re; k++) {
            int2 sw = csr[k];
            float wg = dd * __int_as_float(sw.y);
            size_t b = ((size_t)t*N + sw.x)*5;
            #pragma unroll
            for (int m = 0; m < 5; m++) {
                float2 f2 = xf[b + m];
                acc[2*m]   += wg*f2.x;
                acc[2*m+1] += wg*f2.y;
            }
        }
    }

    float* out = B + (size_t)i*80 + t*16;
    #pragma unroll
    for (int jb = 0; jb < 4; jb++) {
        float4 h = ((const float4*)&w[160])[jb];
        #pragma unroll
        for (int f = 0; f < 10; f++) {
            float4 wv = ((const float4*)w)[f*4 + jb];
            h.x += acc[f]*wv.x; h.y += acc[f]*wv.y;
            h.z += acc[f]*wv.z; h.w += acc[f]*wv.w;
        }
        h.x = fmaxf(h.x, 0.f); h.y = fmaxf(h.y, 0.f);
        h.z = fmaxf(h.z, 0.f); h.w = fmaxf(h.w, 0.f);
        ((float4*)out)[jb] = h;
    }
}

// pass 2 fused: per (node, slice): gather h1 (16 feats) then relu(@W2+b2)
__global__ __launch_bounds__(256)
void k_g2(const float* __restrict__ Fin, const float* __restrict__ dis,
          const float* __restrict__ dinv, const int* __restrict__ row_start,
          const int2* __restrict__ csr, const float* __restrict__ wsW,
          float* __restrict__ B, int N)
{
    __shared__ float w[272];
    for (int j = threadIdx.x; j < 272; j += 256) w[j] = wsW[176 + j];
    __syncthreads();
    int tid = blockIdx.x*256 + threadIdx.x;
    if (tid >= N*5) return;
    int i = tid / 5, t = tid - i*5;

    float dd = dis[i];
    float di = dinv[i];
    int rs = row_start[i], re = row_start[i+1];

    float4 a0, a1, a2, a3;
    {
        const float4* p = (const float4*)(Fin + (size_t)i*80 + t*16);
        a0 = p[0]; a1 = p[1]; a2 = p[2]; a3 = p[3];
        a0.x*=di;a0.y*=di;a0.z*=di;a0.w*=di;
        a1.x*=di;a1.y*=di;a1.z*=di;a1.w*=di;
        a2.x*=di;a2.y*=di;a2.z*=di;a2.w*=di;
        a3.x*=di;a3.y*=di;a3.z*=di;a3.w*=di;
    }
    for (int k = rs; k < re; k++) {
        int2 sw = csr[k];
        float wg = dd * __int_as_float(sw.y);
        const float4* p = (const float4*)(Fin + (size_t)sw.x*80 + t*16);
        float4 v0 = p[0], v1 = p[1], v2 = p[2], v3 = p[3];
        a0.x+=wg*v0.x;a0.y+=wg*v0.y;a0.z+=wg*v0.z;a0.w+=wg*v0.w;
        a1.x+=wg*v1.x;a1.y+=wg*v1.y;a1.z+=wg*v1.z;a1.w+=wg*v1.w;
        a2.x+=wg*v2.x;a2.y+=wg*v2.y;a2.z+=wg*v2.z;a2.w+=wg*v2.w;
        a3.x+=wg*v3.x;a3.y+=wg*v3.y;a3.z+=wg*v3.z;a3.w+=wg*v3.w;
    }
    float acc[16];
    acc[0]=a0.x;acc[1]=a0.y;acc[2]=a0.z;acc[3]=a0.w;
    acc[4]=a1.x;acc[5]=a1.y;acc[6]=a1.z;acc[7]=a1.w;
    acc[8]=a2.x;acc[9]=a2.y;acc[10]=a2.z;acc[11]=a2.w;
    acc[12]=a3.x;acc[13]=a3.y;acc[14]=a3.z;acc[15]=a3.w;

    float* out = B + (size_t)i*80 + t*16;
    #pragma unroll
    for (int jb = 0; jb < 4; jb++) {
        float4 h = ((const float4*)&w[256])[jb];
        #pragma unroll
        for (int f = 0; f < 16; f++) {
            float4 wv = ((const float4*)w)[f*4 + jb];
            h.x += acc[f]*wv.x; h.y += acc[f]*wv.y;
            h.z += acc[f]*wv.z; h.w += acc[f]*wv.w;
        }
        h.x = fmaxf(h.x, 0.f); h.y = fmaxf(h.y, 0.f);
        h.z = fmaxf(h.z, 0.f); h.w = fmaxf(h.w, 0.f);
        ((float4*)out)[jb] = h;
    }
}

// pass 3: pure float4 gather, per (node, 4-feature chunk)
__global__ __launch_bounds__(256)
void k_g3(const float* __restrict__ Fin, const float* __restrict__ dis,
          const float* __restrict__ dinv, const int* __restrict__ row_start,
          const int2* __restrict__ csr, float* __restrict__ Fout, int N)
{
    int tid = blockIdx.x*256 + threadIdx.x;
    if (tid >= N*20) return;
    int i = tid / 20, c = tid - i*20;
    float di = dinv[i], dd = dis[i];
    const float4* fin4 = (const float4*)Fin;
    float4 a = fin4[(size_t)i*20 + c];
    a.x*=di; a.y*=di; a.z*=di; a.w*=di;
    int rs = row_start[i], re = row_start[i+1];
    for (int k = rs; k < re; k++) {
        int2 sw = csr[k];
        float wg = dd * __int_as_float(sw.y);
        float4 v = fin4[(size_t)sw.x*20 + c];
        a.x+=wg*v.x; a.y+=wg*v.y; a.z+=wg*v.z; a.w+=wg*v.w;
    }
    ((float4*)Fout)[(size_t)i*20 + c] = a;
}

// GRU over 5 steps + attention pool + FC + log_softmax, one thread per node.
// Minimal live state; weights broadcast from LDS; logits accumulated directly.
__global__ __launch_bounds__(256, 3)
void k_gru(const float* __restrict__ Pf, const float* __restrict__ wsW,
           const int* __restrict__ flagp, void* __restrict__ out, int N)
{
    __shared__ __align__(16) float sm[1632];
    for (int j = threadIdx.x; j < 1632; j += 256) sm[j] = wsW[4096 + j];
    __syncthreads();

    int i = blockIdx.x*256 + threadIdx.x;
    if (i >= N) return;

    const float4* Az = (const float4*)&sm[0];
    const float4* Ar = (const float4*)&sm[256];
    const float4* Ah = (const float4*)&sm[512];
    const float4* Lz = (const float4*)&sm[768];
    const float4* Lr = (const float4*)&sm[1024];
    const float4* Lh = (const float4*)&sm[1280];

    float H[16];
    #pragma unroll
    for (int j = 0; j < 16; j++) H[j] = 0.f;
    float z0 = sm[1624], z1 = sm[1625];

    for (int t = 0; t < 5; t++) {
        float pf[16];
        {
            const float4* p = (const float4*)(Pf + (size_t)i*80 + t*16);
            #pragma unroll
            for (int jb = 0; jb < 4; jb++) {
                float4 v = p[jb];
                pf[jb*4+0]=v.x; pf[jb*4+1]=v.y; pf[jb*4+2]=v.z; pf[jb*4+3]=v.w;
            }
        }
        float Zg[16];
        #pragma unroll
        for (int jb = 0; jb < 4; jb++) {
            float4 a = ((const float4*)&sm[1536])[jb];
            #pragma unroll
            for (int k = 0; k < 16; k++) {
                float p = pf[k]; float4 wv = Az[k*4+jb];
                a.x += p*wv.x; a.y += p*wv.y; a.z += p*wv.z; a.w += p*wv.w;
            }
            #pragma unroll
            for (int k = 0; k < 16; k++) {
                float h = H[k]; float4 wv = Lz[k*4+jb];
                a.x += h*wv.x; a.y += h*wv.y; a.z += h*wv.z; a.w += h*wv.w;
            }
            Zg[jb*4+0]=sigm(a.x); Zg[jb*4+1]=sigm(a.y);
            Zg[jb*4+2]=sigm(a.z); Zg[jb*4+3]=sigm(a.w);
        }
        float HR[16];
        #pragma unroll
        for (int jb = 0; jb < 4; jb++) {
            float4 a = ((const float4*)&sm[1552])[jb];
            #pragma unroll
            for (int k = 0; k < 16; k++) {
                float p = pf[k]; float4 wv = Ar[k*4+jb];
                a.x += p*wv.x; a.y += p*wv.y; a.z += p*wv.z; a.w += p*wv.w;
            }
            #pragma unroll
            for (int k = 0; k < 16; k++) {
                float h = H[k]; float4 wv = Lr[k*4+jb];
                a.x += h*wv.x; a.y += h*wv.y; a.z += h*wv.z; a.w += h*wv.w;
            }
            HR[jb*4+0]=H[jb*4+0]*sigm(a.x); HR[jb*4+1]=H[jb*4+1]*sigm(a.y);
            HR[jb*4+2]=H[jb*4+2]*sigm(a.z); HR[jb*4+3]=H[jb*4+3]*sigm(a.w);
        }
        #pragma unroll
        for (int jb = 0; jb < 4; jb++) {
            float4 a = ((const float4*)&sm[1568])[jb];
            #pragma unroll
            for (int k = 0; k < 16; k++) {
                float p = pf[k]; float4 wv = Ah[k*4+jb];
                a.x += p*wv.x; a.y += p*wv.y; a.z += p*wv.z; a.w += p*wv.w;
            }
            #pragma unroll
            for (int k = 0; k < 16; k++) {
                float h = HR[k]; float4 wv = Lh[k*4+jb];
                a.x += h*wv.x; a.y += h*wv.y; a.z += h*wv.z; a.w += h*wv.w;
            }
            #pragma unroll
            for (int q = 0; q < 4; q++) {
                int j = jb*4 + q;
                float v = (q==0)?a.x:(q==1)?a.y:(q==2)?a.z:a.w;
                v = fminf(fmaxf(v, -15.f), 15.f);
                float ex = __expf(2.f*v);
                float th = (ex - 1.f) / (ex + 1.f);
                float z = Zg[j];
                H[j] = z*H[j] + (1.f - z)*th;
            }
        }
        float pr = sm[1584 + t];
        float s0 = 0.f, s1 = 0.f;
        #pragma unroll
        for (int k = 0; k < 16; k++) {
            s0 += H[k]*sm[1592 + k*2];
            s1 += H[k]*sm[1592 + k*2 + 1];
        }
        z0 += pr*s0; z1 += pr*s1;
    }

    float mm = fmaxf(z0, z1);
    float l  = __logf(__expf(z0-mm) + __expf(z1-mm));
    float o0 = z0 - mm - l, o1 = z1 - mm - l;
    if (flagp[0]) {
        __hip_bfloat162 h2;
        h2.x = __float2bfloat16(o0);
        h2.y = __float2bfloat16(o1);
        ((__hip_bfloat162*)out)[i] = h2;
    } else {
        ((float2*)out)[i] = make_float2(o0, o1);
    }
}

extern "C" void kernel_launch(void* const* d_in, const int* in_sizes, int n_in,
                              void* d_out, int out_size, void* d_ws, size_t ws_size,
                              hipStream_t stream)
{
    const void* x   = d_in[0];
    const int* src  = (const int*)d_in[1];
    const int* dst  = (const int*)d_in[2];
    int N = in_sizes[0] / 50;     // T*F_IN = 50
    int E = in_sizes[1];

    char* ws = (char*)d_ws;
    size_t off = 0;
    auto alloc = [&](size_t bytes) -> void* {
        void* p = ws + off;
        off = (off + bytes + 255) & ~(size_t)255;
        return p;
    };
    int*   flagp     = (int*)  alloc(64);
    float* wsW       = (float*)alloc(8192*4);
    int*   deg       = (int*)  alloc((size_t)N*4);
    float* dis       = (float*)alloc((size_t)N*4);
    float* dinv      = (float*)alloc((size_t)N*4);
    int*   row_start = (int*)  alloc(((size_t)N+1)*4);
    int*   cursor    = (int*)  alloc((size_t)N*4);
    int*   bsum      = (int*)  alloc(4096);
    int*   boff      = (int*)  alloc(4096);
    int2*  csr       = (int2*) alloc((size_t)E*8);
    float* bufA      = (float*)alloc((size_t)N*80*4);
    float* bufB      = (float*)alloc((size_t)N*80*4);

    int nb = (N + 255) / 256;
    int gE = (E + 255) / 256;

    hipMemsetAsync(deg, 0, (size_t)N*4, stream);

    WPtrs wp;
    for (int a = 0; a < 19; a++) wp.p[a] = d_in[3 + a];
    k_prep<<<1, 256, 0, stream>>>(x, wp, flagp, wsW);

    k_deg   <<<gE, 256, 0, stream>>>(dst, deg, E);
    k_scan_a<<<nb, 256, 0, stream>>>(deg, dis, dinv, bsum, N);
    k_scan_b<<<1, 512, 0, stream>>>(bsum, boff, nb);
    k_scan_c<<<nb, 256, 0, stream>>>(deg, boff, row_start, cursor, N, E);
    k_fill  <<<gE, 256, 0, stream>>>(src, dst, dis, cursor, csr, E);

    int g5  = ((size_t)N*5  + 255) / 256;
    int g20 = ((size_t)N*20 + 255) / 256;

    k_g1 <<<g5,  256, 0, stream>>>(x, flagp, dis, dinv, row_start, csr, wsW, bufA, N);
    k_g2 <<<g5,  256, 0, stream>>>(bufA, dis, dinv, row_start, csr, wsW, bufB, N);
    k_g3 <<<g20, 256, 0, stream>>>(bufB, dis, dinv, row_start, csr, bufA, N);
    k_gru<<<nb,  256, 0, stream>>>(bufA, wsW, flagp, d_out, N);
}